// Round 2
// baseline (498.323 us; speedup 1.0000x reference)
//
#include <hip/hip_runtime.h>
#include <math.h>

// ArcFaceLoss: B=512, D=512, C=100000, margin=0.5, scale=64
// Pipeline:
//   1) pack_x:    normalize x rows -> bf16, prepacked chunk-major layout for global_load_lds
//   2) cosphi:    per-row fp32-accurate cos_t / phi_t (gather of 512 weight rows)
//   3) gemm_lse:  fused bf16-MFMA GEMM + exp(64*cos-64) row-sum (fixed max offset 64),
//                 weight normalization fused into LDS staging (read weight from HBM ONCE).
//                 v2 (resubmit after infra failure): double-buffered LDS +
//                 prefetch-before-compute (T3 minimum 2-phase), one barrier per chunk.
//   4) finalize:  corrected sum (-e_cos + e_phi), lse = 64 + log(S), mean over batch

#define NB 512
#define ND 512
#define NC 100000
#define BK 32
#define NCHUNK 16          // ND / BK
#define CT 64              // classes per block
#define FSCALE 64.0f
#define C_COS_M 0.8775825618903728f
#define C_SIN_M 0.479425538604203f
#define C_TH  (-0.8775825618903728f)   // cos(pi - m)
#define C_MM  0.2397127693021015f      // sin(pi - m) * m

typedef __bf16 bf16x8 __attribute__((ext_vector_type(8)));
typedef __bf16 bf16x4 __attribute__((ext_vector_type(4)));
typedef float  f32x4  __attribute__((ext_vector_type(4)));
typedef __attribute__((address_space(1))) unsigned int GU;
typedef __attribute__((address_space(3))) unsigned int LU;

// ---------------- 1) normalize + pack x ----------------
// xp layout: [chunk=k/32][row][k%32] bf16, so each 32K-chunk of all 512 rows is
// one contiguous 32KB block -> global_load_lds-friendly.
__global__ void pack_x_kernel(const float* __restrict__ x, __bf16* __restrict__ xp) {
  const int b = blockIdx.x;
  const int t = threadIdx.x;                   // 0..127
  float4 v = reinterpret_cast<const float4*>(x + (size_t)b * ND)[t];
  float ss = v.x*v.x + v.y*v.y + v.z*v.z + v.w*v.w;
  #pragma unroll
  for (int m = 1; m < 64; m <<= 1) ss += __shfl_xor(ss, m);
  __shared__ float sred[2];
  if ((t & 63) == 0) sred[t >> 6] = ss;
  __syncthreads();
  const float rn = rsqrtf(fmaxf(sred[0] + sred[1], 1e-24f));
  bf16x4 o;
  o[0] = (__bf16)(v.x * rn); o[1] = (__bf16)(v.y * rn);
  o[2] = (__bf16)(v.z * rn); o[3] = (__bf16)(v.w * rn);
  const int k = 4 * t;
  __bf16* dst = xp + ((size_t)(k >> 5) * NB + b) * BK + (k & 31);
  *reinterpret_cast<bf16x4*>(dst) = o;
}

// ---------------- 2) fp32-accurate target cosine + phi ----------------
__global__ void cosphi_kernel(const float* __restrict__ x, const float* __restrict__ w,
                              const int* __restrict__ tgt,
                              float* __restrict__ cos_t, float* __restrict__ phi_t) {
  const int b = blockIdx.x;
  const int lane = threadIdx.x;                // 0..63
  const int t = tgt[b];
  const float4* xr = reinterpret_cast<const float4*>(x + (size_t)b * ND);
  const float4* wr = reinterpret_cast<const float4*>(w + (size_t)t * ND);
  float dp = 0.f, xs = 0.f, ws = 0.f;
  #pragma unroll
  for (int j = 0; j < 2; ++j) {
    float4 xv = xr[lane * 2 + j];
    float4 wv = wr[lane * 2 + j];
    dp += xv.x*wv.x + xv.y*wv.y + xv.z*wv.z + xv.w*wv.w;
    xs += xv.x*xv.x + xv.y*xv.y + xv.z*xv.z + xv.w*xv.w;
    ws += wv.x*wv.x + wv.y*wv.y + wv.z*wv.z + wv.w*wv.w;
  }
  #pragma unroll
  for (int m = 1; m < 64; m <<= 1) {
    dp += __shfl_xor(dp, m);
    xs += __shfl_xor(xs, m);
    ws += __shfl_xor(ws, m);
  }
  if (lane == 0) {
    float c = dp * rsqrtf(fmaxf(xs, 1e-24f)) * rsqrtf(fmaxf(ws, 1e-24f));
    c = fminf(fmaxf(c, -1.f), 1.f);
    float s = sqrtf(fmaxf(1.f - c * c, 0.f));
    float phi = c * C_COS_M - s * C_SIN_M;
    phi = (c > C_TH) ? phi : (c - C_MM);
    cos_t[b] = c;
    phi_t[b] = phi;
  }
}

// ---------------- 3) fused GEMM + partial sum-exp (v2: pipelined) ----------------
// Block: 512 threads (8 waves). Block tile: all 512 batch rows x 64 classes.
// Wave w owns rows [64w, 64w+64) x all 64 classes: 4x4 tiles of mfma 16x16x32 bf16.
// Weight rows are read from HBM exactly once (fp32), normalized-on-the-fly:
// sumsq accumulated in registers during staging, rsqrt applied in epilogue.
// Schedule per chunk c (single barrier):
//   issue W(c+1) global load (HBM, longest latency) + A(c+1) global_load_lds (L2)
//   -> ds_read + 16 MFMA on chunk c (covers the load latency)
//   -> convert/ds_write W(c+1) -> __syncthreads (vmcnt/lgkm drain + barrier).
__global__ __launch_bounds__(512, 4) void gemm_lse_kernel(
    const __bf16* __restrict__ xp, const float* __restrict__ w,
    float* __restrict__ gsum) {
  __shared__ __align__(16) __bf16 As[2][NB * BK];   // 2 x 32 KB
  __shared__ __align__(16) __bf16 Bs[2][CT * BK];   // 2 x 4 KB
  __shared__ float wss[CT];

  const int tid  = threadIdx.x;
  const int wv   = tid >> 6;
  const int lane = tid & 63;
  const int bc   = blockIdx.x * CT;

  // weight staging role: row wr (0..63), 16B-part wp (0..7)
  const int wr = tid >> 3;
  const int wp = tid & 7;
  const long long wrow = (long long)min(bc + wr, NC - 1);
  const float4* wsrc = reinterpret_cast<const float4*>(w + wrow * (long long)ND);

  float wsq = 0.f;
  f32x4 acc[4][4] = {};

  const int m_w = wv * 64;
  const int qa  = (lane >> 4) * 8;   // k-offset of this lane's frag
  const int ra  = lane & 15;         // row/col within 16-tile

  // ---- prologue: stage chunk 0 into buffer 0 ----
  {
    float4 v = wsrc[wp];                         // W chunk 0 (HBM)
    const char* g = reinterpret_cast<const char*>(xp) + wv * 1024 + lane * 16;
    char* l = reinterpret_cast<char*>(&As[0][0]) + wv * 1024;  // wave-uniform base
    #pragma unroll
    for (int j = 0; j < 4; ++j)
      __builtin_amdgcn_global_load_lds((GU*)(g + j * 8192), (LU*)(l + j * 8192),
                                       16, 0, 0);
    wsq += v.x*v.x + v.y*v.y + v.z*v.z + v.w*v.w;
    bf16x4 pk;
    pk[0] = (__bf16)v.x; pk[1] = (__bf16)v.y;
    pk[2] = (__bf16)v.z; pk[3] = (__bf16)v.w;
    *reinterpret_cast<bf16x4*>(&Bs[0][wr * BK + wp * 4]) = pk;
  }
  __syncthreads();

  for (int c = 0; c < NCHUNK; ++c) {
    const int cur = c & 1;
    const bool more = (c + 1 < NCHUNK);
    float4 vn;
    if (more) {
      // issue next-chunk loads BEFORE compute: W first (HBM ~900cy), then A (L2)
      vn = wsrc[(c + 1) * 8 + wp];
      const char* g = reinterpret_cast<const char*>(xp)
                      + (size_t)(c + 1) * (NB * BK * 2) + wv * 1024 + lane * 16;
      char* l = reinterpret_cast<char*>(&As[cur ^ 1][0]) + wv * 1024;
      #pragma unroll
      for (int j = 0; j < 4; ++j)
        __builtin_amdgcn_global_load_lds((GU*)(g + j * 8192), (LU*)(l + j * 8192),
                                         16, 0, 0);
    }

    // --- compute chunk c: 8 x ds_read_b128 + 16 MFMA per wave ---
    bf16x8 af[4], bfr[4];
    #pragma unroll
    for (int rt = 0; rt < 4; ++rt)
      af[rt] = *reinterpret_cast<const bf16x8*>(&As[cur][(m_w + rt * 16 + ra) * BK + qa]);
    #pragma unroll
    for (int ct = 0; ct < 4; ++ct)
      bfr[ct] = *reinterpret_cast<const bf16x8*>(&Bs[cur][(ct * 16 + ra) * BK + qa]);
    #pragma unroll
    for (int rt = 0; rt < 4; ++rt)
      #pragma unroll
      for (int ct = 0; ct < 4; ++ct)
        acc[rt][ct] = __builtin_amdgcn_mfma_f32_16x16x32_bf16(af[rt], bfr[ct],
                                                              acc[rt][ct], 0, 0, 0);

    if (more) {
      // W(c+1): sumsq accumulate + bf16 convert -> LDS (other buffer)
      wsq += vn.x*vn.x + vn.y*vn.y + vn.z*vn.z + vn.w*vn.w;
      bf16x4 pk;
      pk[0] = (__bf16)vn.x; pk[1] = (__bf16)vn.y;
      pk[2] = (__bf16)vn.z; pk[3] = (__bf16)vn.w;
      *reinterpret_cast<bf16x4*>(&Bs[cur ^ 1][wr * BK + wp * 4]) = pk;
    }
    __syncthreads();   // publishes buffer cur^1 (vmcnt+lgkm drained here)
  }

  // reduce weight sumsq across the 8 lanes sharing a row
  wsq += __shfl_xor(wsq, 1);
  wsq += __shfl_xor(wsq, 2);
  wsq += __shfl_xor(wsq, 4);
  if (wp == 0) wss[wr] = wsq;
  __syncthreads();

  // --- epilogue: cosine = acc * rsqrt(|w|^2); e = exp(64*cos - 64); row-sum ---
  // C/D layout (16x16): col = lane&15, row = (lane>>4)*4 + reg
  const int col_l = lane & 15;
  const int quad  = lane >> 4;
  float rnw[4];
  int   vmask[4];
  #pragma unroll
  for (int ct = 0; ct < 4; ++ct) {
    rnw[ct]   = rsqrtf(fmaxf(wss[ct * 16 + col_l], 1e-24f));
    vmask[ct] = (bc + ct * 16 + col_l) < NC;
  }
  #pragma unroll
  for (int rt = 0; rt < 4; ++rt) {
    #pragma unroll
    for (int r = 0; r < 4; ++r) {
      float es = 0.f;
      #pragma unroll
      for (int ct = 0; ct < 4; ++ct) {
        float cosv = acc[rt][ct][r] * rnw[ct];
        float e = __expf(fmaf(FSCALE, cosv, -FSCALE));
        es += vmask[ct] ? e : 0.f;
      }
      // sum over the 16 columns (lanes within each 16-lane group)
      es += __shfl_xor(es, 1);
      es += __shfl_xor(es, 2);
      es += __shfl_xor(es, 4);
      es += __shfl_xor(es, 8);
      if (col_l == 0) {
        atomicAdd(&gsum[m_w + rt * 16 + quad * 4 + r], es);
      }
    }
  }
}

// ---------------- 4) finalize ----------------
__global__ void finalize_kernel(const float* __restrict__ gsum,
                                const float* __restrict__ cos_t,
                                const float* __restrict__ phi_t,
                                float* __restrict__ out) {
  const int b = threadIdx.x;   // 512
  const float c = cos_t[b];
  const float p = phi_t[b];
  float corr = gsum[b] - __expf(fmaf(FSCALE, c, -FSCALE))
                       + __expf(fmaf(FSCALE, p, -FSCALE));
  corr = fmaxf(corr, 1e-38f);
  float lb = FSCALE + logf(corr) - FSCALE * p;
  #pragma unroll
  for (int m = 1; m < 64; m <<= 1) lb += __shfl_xor(lb, m);
  __shared__ float pr[8];
  if ((b & 63) == 0) pr[b >> 6] = lb;
  __syncthreads();
  if (b == 0) {
    float tot = 0.f;
    #pragma unroll
    for (int j = 0; j < 8; ++j) tot += pr[j];
    out[0] = tot * (1.0f / NB);
  }
}

extern "C" void kernel_launch(void* const* d_in, const int* in_sizes, int n_in,
                              void* d_out, int out_size, void* d_ws, size_t ws_size,
                              hipStream_t stream) {
  const float* x  = (const float*)d_in[0];
  const float* w  = (const float*)d_in[1];
  const int* tgt  = (const int*)d_in[2];
  float* out      = (float*)d_out;

  // workspace layout: xp (512 KB) | gsum (2 KB) | cos_t (2 KB) | phi_t (2 KB)
  __bf16* xp   = (__bf16*)d_ws;
  float* gsum  = (float*)((char*)d_ws + (size_t)NB * ND * 2);
  float* cos_t = gsum + NB;
  float* phi_t = cos_t + NB;

  hipMemsetAsync(gsum, 0, NB * sizeof(float), stream);
  pack_x_kernel<<<NB, 128, 0, stream>>>(x, xp);
  cosphi_kernel<<<NB, 64, 0, stream>>>(x, w, tgt, cos_t, phi_t);
  const int nblk = (NC + CT - 1) / CT;   // 1563
  gemm_lse_kernel<<<nblk, 512, 0, stream>>>(xp, w, gsum);
  finalize_kernel<<<1, 512, 0, stream>>>(gsum, cos_t, phi_t, out);
}

// Round 3
// 449.771 us; speedup vs baseline: 1.1079x; 1.1079x over previous
//
#include <hip/hip_runtime.h>
#include <math.h>

// ArcFaceLoss: B=512, D=512, C=100000, margin=0.5, scale=64
// Pipeline:
//   1) pack_x:    normalize x rows -> bf16, prepacked chunk-major SWIZZLED layout
//                 (bank-conflict-free ds_read_b128 after global_load_lds, T2+T21)
//   2) cosphi:    per-row fp32-accurate cos_t / phi_t
//   3) gemm_lse:  v3 - B-tile (64 classes x 512) staged ONCE into resident LDS
//                 (fp32 read + sumsq + bf16 convert upfront, nothing staged through
//                 registers inside the k-loop). A double-buffered via global_load_lds.
//                 1024 threads / 16 waves, LDS = 128 KiB, 1 block/CU, 16 waves/CU.
//   4) finalize:  corrected sum (-e_cos + e_phi), lse = 64 + log(S), mean over batch

#define NB 512
#define ND 512
#define NC 100000
#define BK 32
#define NCHUNK 16          // ND / BK
#define CT 64              // classes per block
#define FSCALE 64.0f
#define C_COS_M 0.8775825618903728f
#define C_SIN_M 0.479425538604203f
#define C_TH  (-0.8775825618903728f)   // cos(pi - m)
#define C_MM  0.2397127693021015f      // sin(pi - m) * m

// XOR-swizzle within each 32KB (A) / 4KB (B) tile: slot bits [5:4] ^= row bits [8:7].
// Involutive; preserves bits [3:0] so 8B/16B accesses stay aligned. Spreads the
// 16-lane quarter-wave (16 rows, same slot) across all 8 bank-groups -> 2-way (free).
#define SWZ(b) ((b) ^ (((b) >> 3) & 48))

typedef __bf16 bf16x8 __attribute__((ext_vector_type(8)));
typedef __bf16 bf16x4 __attribute__((ext_vector_type(4)));
typedef float  f32x4  __attribute__((ext_vector_type(4)));
typedef __attribute__((address_space(1))) unsigned int GU;
typedef __attribute__((address_space(3))) unsigned int LU;

// ---------------- 1) normalize + pack x (swizzled chunk-major) ----------------
// xp layout: 16 chunk-blocks of 32KB; within a chunk-block, byte lb = row*64 + (k%32)*2
// is stored at SWZ(lb). global_load_lds copies each 32KB block linearly, so the LDS
// tile inherits the swizzle and ds_read uses SWZ'd offsets (T21: pre-swizzled source).
__global__ void pack_x_kernel(const float* __restrict__ x, __bf16* __restrict__ xp) {
  const int b = blockIdx.x;
  const int t = threadIdx.x;                   // 0..127
  float4 v = reinterpret_cast<const float4*>(x + (size_t)b * ND)[t];
  float ss = v.x*v.x + v.y*v.y + v.z*v.z + v.w*v.w;
  #pragma unroll
  for (int m = 1; m < 64; m <<= 1) ss += __shfl_xor(ss, m);
  __shared__ float sred[2];
  if ((t & 63) == 0) sred[t >> 6] = ss;
  __syncthreads();
  const float rn = rsqrtf(fmaxf(sred[0] + sred[1], 1e-24f));
  bf16x4 o;
  o[0] = (__bf16)(v.x * rn); o[1] = (__bf16)(v.y * rn);
  o[2] = (__bf16)(v.z * rn); o[3] = (__bf16)(v.w * rn);
  const int k = 4 * t;                         // element index 0..508
  const int chunk = k >> 5;
  const int lb = b * 64 + (k & 31) * 2;        // logical byte within chunk-block
  char* dst = (char*)xp + (size_t)chunk * (NB * BK * 2) + SWZ(lb);
  *reinterpret_cast<bf16x4*>(dst) = o;
}

// ---------------- 2) fp32-accurate target cosine + phi ----------------
__global__ void cosphi_kernel(const float* __restrict__ x, const float* __restrict__ w,
                              const int* __restrict__ tgt,
                              float* __restrict__ cos_t, float* __restrict__ phi_t) {
  const int b = blockIdx.x;
  const int lane = threadIdx.x;                // 0..63
  const int t = tgt[b];
  const float4* xr = reinterpret_cast<const float4*>(x + (size_t)b * ND);
  const float4* wr = reinterpret_cast<const float4*>(w + (size_t)t * ND);
  float dp = 0.f, xs = 0.f, ws = 0.f;
  #pragma unroll
  for (int j = 0; j < 2; ++j) {
    float4 xv = xr[lane * 2 + j];
    float4 wv = wr[lane * 2 + j];
    dp += xv.x*wv.x + xv.y*wv.y + xv.z*wv.z + xv.w*wv.w;
    xs += xv.x*xv.x + xv.y*xv.y + xv.z*xv.z + xv.w*xv.w;
    ws += wv.x*wv.x + wv.y*wv.y + wv.z*wv.z + wv.w*wv.w;
  }
  #pragma unroll
  for (int m = 1; m < 64; m <<= 1) {
    dp += __shfl_xor(dp, m);
    xs += __shfl_xor(xs, m);
    ws += __shfl_xor(ws, m);
  }
  if (lane == 0) {
    float c = dp * rsqrtf(fmaxf(xs, 1e-24f)) * rsqrtf(fmaxf(ws, 1e-24f));
    c = fminf(fmaxf(c, -1.f), 1.f);
    float s = sqrtf(fmaxf(1.f - c * c, 0.f));
    float phi = c * C_COS_M - s * C_SIN_M;
    phi = (c > C_TH) ? phi : (c - C_MM);
    cos_t[b] = c;
    phi_t[b] = phi;
  }
}

// ---------------- 3) fused GEMM + partial sum-exp (v3: resident B) ----------------
// 1024 threads = 16 waves. Block tile: 512 rows x 64 classes. Wave wv owns rows
// [32*wv, 32*wv+32) x 64 classes: 2x4 tiles of mfma 16x16x32 bf16.
// Upfront: stage whole W-tile (64 rows fp32 -> bf16, swizzled) into resident LDS,
// sumsq in-register (wsq survives the k-loop in ONE VGPR). k-loop stages only A
// via global_load_lds (dbuf, 1-deep prefetch, single barrier) - no registers, no VALU.
__global__ __launch_bounds__(1024) void gemm_lse_kernel(
    const __bf16* __restrict__ xp, const float* __restrict__ w,
    float* __restrict__ gsum) {
  __shared__ __align__(16) char As[2 * NB * BK * 2];    // 2 x 32 KB (dbuf, swizzled)
  __shared__ __align__(16) char Bs[NCHUNK * CT * BK * 2]; // 64 KB resident (swizzled)

  const int tid  = threadIdx.x;
  const int wv   = tid >> 6;          // 0..15
  const int lane = tid & 63;
  const int bc   = blockIdx.x * CT;

  // ---- prologue A: issue chunk-0 global_load_lds (in flight during W staging) ----
  {
    const char* g = (const char*)xp + wv * 1024 + lane * 16;
    char* l = As + wv * 1024;                  // wave-uniform base
    __builtin_amdgcn_global_load_lds((GU*)g,           (LU*)l,           16, 0, 0);
    __builtin_amdgcn_global_load_lds((GU*)(g + 16384), (LU*)(l + 16384), 16, 0, 0);
  }

  // ---- upfront W staging: 64 rows x 512 fp32 -> bf16 swizzled LDS + sumsq ----
  const int r  = tid >> 4;            // class row 0..63
  const int wp = tid & 15;            // 16 threads per row
  const long long wrow = (long long)min(bc + r, NC - 1);
  const float4* wsrc = reinterpret_cast<const float4*>(w + wrow * (long long)ND);
  float wsq = 0.f;
  #pragma unroll
  for (int i = 0; i < 8; ++i) {
    float4 v = wsrc[i * 16 + wp];
    wsq += v.x*v.x + v.y*v.y + v.z*v.z + v.w*v.w;
    bf16x4 pk;
    pk[0] = (__bf16)v.x; pk[1] = (__bf16)v.y;
    pk[2] = (__bf16)v.z; pk[3] = (__bf16)v.w;
    const int k4 = (i * 16 + wp) * 4;          // element index 0..508
    const int chunk = k4 >> 5;
    const int lb = r * 64 + (k4 & 31) * 2;     // logical byte within 4KB chunk tile
    *reinterpret_cast<bf16x4*>(Bs + chunk * (CT * BK * 2) + SWZ(lb)) = pk;
  }
  __syncthreads();   // drains chunk-0 A glds + all Bs writes

  // ---- fragment offsets (loop-invariant, swizzled) ----
  const int m_w = wv * 32;
  const int ra  = lane & 15;
  const int qb  = (lane >> 4) * 16;   // byte offset of this lane's 16B k-slot
  int aoff[2], boff[4];
  #pragma unroll
  for (int rt = 0; rt < 2; ++rt) {
    const int lb = (m_w + rt * 16 + ra) * 64 + qb;
    aoff[rt] = SWZ(lb);
  }
  #pragma unroll
  for (int ct = 0; ct < 4; ++ct) {
    const int lb = (ct * 16 + ra) * 64 + qb;
    boff[ct] = SWZ(lb);
  }

  f32x4 acc[2][4] = {};

  for (int c = 0; c < NCHUNK; ++c) {
    const int cur = c & 1;
    if (c + 1 < NCHUNK) {
      // prefetch A(c+1) into the other buffer (pure async, no registers)
      const char* g = (const char*)xp + (size_t)(c + 1) * (NB * BK * 2)
                      + wv * 1024 + lane * 16;
      char* l = As + (cur ^ 1) * (NB * BK * 2) + wv * 1024;
      __builtin_amdgcn_global_load_lds((GU*)g,           (LU*)l,           16, 0, 0);
      __builtin_amdgcn_global_load_lds((GU*)(g + 16384), (LU*)(l + 16384), 16, 0, 0);
    }

    // compute chunk c: 2+4 ds_read_b128 + 8 MFMA per wave
    bf16x8 af[2], bfr[4];
    #pragma unroll
    for (int rt = 0; rt < 2; ++rt)
      af[rt] = *reinterpret_cast<const bf16x8*>(As + cur * (NB * BK * 2) + aoff[rt]);
    #pragma unroll
    for (int ct = 0; ct < 4; ++ct)
      bfr[ct] = *reinterpret_cast<const bf16x8*>(Bs + c * (CT * BK * 2) + boff[ct]);
    #pragma unroll
    for (int rt = 0; rt < 2; ++rt)
      #pragma unroll
      for (int ct = 0; ct < 4; ++ct)
        acc[rt][ct] = __builtin_amdgcn_mfma_f32_16x16x32_bf16(af[rt], bfr[ct],
                                                              acc[rt][ct], 0, 0, 0);
    __syncthreads();   // publishes As[cur^1] (vmcnt+lgkm drained)
  }

  // ---- weight sumsq: reduce across the 16 threads sharing a row ----
  wsq += __shfl_xor(wsq, 1);
  wsq += __shfl_xor(wsq, 2);
  wsq += __shfl_xor(wsq, 4);
  wsq += __shfl_xor(wsq, 8);
  float* wss = reinterpret_cast<float*>(As);   // As is dead; reuse 256 B
  if (wp == 0) wss[r] = wsq;
  __syncthreads();

  // ---- epilogue: cosine = acc * rsqrt(|w|^2); e = exp(64*cos - 64); row-sum ----
  // C/D layout (16x16): col = lane&15, row = (lane>>4)*4 + reg
  const int col_l = lane & 15;
  const int quad  = lane >> 4;
  float rnw[4];
  int   vmask[4];
  #pragma unroll
  for (int ct = 0; ct < 4; ++ct) {
    rnw[ct]   = rsqrtf(fmaxf(wss[ct * 16 + col_l], 1e-24f));
    vmask[ct] = (bc + ct * 16 + col_l) < NC;
  }
  #pragma unroll
  for (int rt = 0; rt < 2; ++rt) {
    #pragma unroll
    for (int rg = 0; rg < 4; ++rg) {
      float es = 0.f;
      #pragma unroll
      for (int ct = 0; ct < 4; ++ct) {
        float cosv = acc[rt][ct][rg] * rnw[ct];
        float e = __expf(fmaf(FSCALE, cosv, -FSCALE));
        es += vmask[ct] ? e : 0.f;
      }
      // sum over the 16 columns (lanes within each 16-lane group)
      es += __shfl_xor(es, 1);
      es += __shfl_xor(es, 2);
      es += __shfl_xor(es, 4);
      es += __shfl_xor(es, 8);
      if (col_l == 0) {
        atomicAdd(&gsum[m_w + rt * 16 + quad * 4 + rg], es);
      }
    }
  }
}

// ---------------- 4) finalize ----------------
__global__ void finalize_kernel(const float* __restrict__ gsum,
                                const float* __restrict__ cos_t,
                                const float* __restrict__ phi_t,
                                float* __restrict__ out) {
  const int b = threadIdx.x;   // 512
  const float c = cos_t[b];
  const float p = phi_t[b];
  float corr = gsum[b] - __expf(fmaf(FSCALE, c, -FSCALE))
                       + __expf(fmaf(FSCALE, p, -FSCALE));
  corr = fmaxf(corr, 1e-38f);
  float lb = FSCALE + logf(corr) - FSCALE * p;
  #pragma unroll
  for (int m = 1; m < 64; m <<= 1) lb += __shfl_xor(lb, m);
  __shared__ float pr[8];
  if ((b & 63) == 0) pr[b >> 6] = lb;
  __syncthreads();
  if (b == 0) {
    float tot = 0.f;
    #pragma unroll
    for (int j = 0; j < 8; ++j) tot += pr[j];
    out[0] = tot * (1.0f / NB);
  }
}

extern "C" void kernel_launch(void* const* d_in, const int* in_sizes, int n_in,
                              void* d_out, int out_size, void* d_ws, size_t ws_size,
                              hipStream_t stream) {
  const float* x  = (const float*)d_in[0];
  const float* w  = (const float*)d_in[1];
  const int* tgt  = (const int*)d_in[2];
  float* out      = (float*)d_out;

  // workspace layout: xp (512 KB) | gsum (2 KB) | cos_t (2 KB) | phi_t (2 KB)
  __bf16* xp   = (__bf16*)d_ws;
  float* gsum  = (float*)((char*)d_ws + (size_t)NB * ND * 2);
  float* cos_t = gsum + NB;
  float* phi_t = cos_t + NB;

  hipMemsetAsync(gsum, 0, NB * sizeof(float), stream);
  pack_x_kernel<<<NB, 128, 0, stream>>>(x, xp);
  cosphi_kernel<<<NB, 64, 0, stream>>>(x, w, tgt, cos_t, phi_t);
  const int nblk = (NC + CT - 1) / CT;   // 1563
  gemm_lse_kernel<<<nblk, 1024, 0, stream>>>(xp, w, gsum);
  finalize_kernel<<<1, 512, 0, stream>>>(gsum, cos_t, phi_t, out);
}

// Round 4
// 381.943 us; speedup vs baseline: 1.3047x; 1.1776x over previous
//
#include <hip/hip_runtime.h>
#include <math.h>

// ArcFaceLoss: B=512, D=512, C=100000, margin=0.5, scale=64
// v4:
//   - gsum atomics spread over 64 replicas (was 800K atomics onto 8 cache lines ->
//     L2 same-line serialization floor); finalize sums replicas.
//   - gemm: 512 thr / 8 waves, wave = 64 rows x 64 cls (4x4 frags). Weight streamed
//     PER-CHUNK as raw fp32 via global_load_lds (no register staging -> no spill),
//     bf16 convert + sumsq done at consume time in-register. LDS = 2x32K (A) +
//     2x8K (W fp32) = 80 KB exactly -> 2 blocks/CU for cross-block latency hiding.
//   - W LDS tile XOR-swizzled via pre-swizzled glds SOURCE addresses (T21).

#define NB 512
#define ND 512
#define NC 100000
#define BK 32
#define NCHUNK 16          // ND / BK
#define CT 64              // classes per block
#define REP 64             // gsum replicas (atomic decongestion)
#define FSCALE 64.0f
#define C_COS_M 0.8775825618903728f
#define C_SIN_M 0.479425538604203f
#define C_TH  (-0.8775825618903728f)   // cos(pi - m)
#define C_MM  0.2397127693021015f      // sin(pi - m) * m

// A-tile swizzle (unchanged from v3, proven): bits[5:4] ^= bits[8:7]
#define SWZA(b) ((b) ^ (((b) >> 3) & 48))
// W-tile swizzle (fp32 rows, 128 B): bits[6:4] ^= bits[9:7]  (involutive)
#define SWZW(b) ((b) ^ (((b) >> 3) & 112))

typedef __bf16 bf16x8 __attribute__((ext_vector_type(8)));
typedef __bf16 bf16x4 __attribute__((ext_vector_type(4)));
typedef float  f32x4  __attribute__((ext_vector_type(4)));
typedef __attribute__((address_space(1))) unsigned int GU;
typedef __attribute__((address_space(3))) unsigned int LU;

// ---------------- 1) normalize + pack x (swizzled chunk-major, unchanged) ----------------
__global__ void pack_x_kernel(const float* __restrict__ x, __bf16* __restrict__ xp) {
  const int b = blockIdx.x;
  const int t = threadIdx.x;                   // 0..127
  float4 v = reinterpret_cast<const float4*>(x + (size_t)b * ND)[t];
  float ss = v.x*v.x + v.y*v.y + v.z*v.z + v.w*v.w;
  #pragma unroll
  for (int m = 1; m < 64; m <<= 1) ss += __shfl_xor(ss, m);
  __shared__ float sred[2];
  if ((t & 63) == 0) sred[t >> 6] = ss;
  __syncthreads();
  const float rn = rsqrtf(fmaxf(sred[0] + sred[1], 1e-24f));
  bf16x4 o;
  o[0] = (__bf16)(v.x * rn); o[1] = (__bf16)(v.y * rn);
  o[2] = (__bf16)(v.z * rn); o[3] = (__bf16)(v.w * rn);
  const int k = 4 * t;                         // element index 0..508
  const int chunk = k >> 5;
  const int lb = b * 64 + (k & 31) * 2;        // logical byte within 32KB chunk-block
  char* dst = (char*)xp + (size_t)chunk * (NB * BK * 2) + SWZA(lb);
  *reinterpret_cast<bf16x4*>(dst) = o;
}

// ---------------- 2) fp32-accurate target cosine + phi (unchanged) ----------------
__global__ void cosphi_kernel(const float* __restrict__ x, const float* __restrict__ w,
                              const int* __restrict__ tgt,
                              float* __restrict__ cos_t, float* __restrict__ phi_t) {
  const int b = blockIdx.x;
  const int lane = threadIdx.x;                // 0..63
  const int t = tgt[b];
  const float4* xr = reinterpret_cast<const float4*>(x + (size_t)b * ND);
  const float4* wr = reinterpret_cast<const float4*>(w + (size_t)t * ND);
  float dp = 0.f, xs = 0.f, ws = 0.f;
  #pragma unroll
  for (int j = 0; j < 2; ++j) {
    float4 xv = xr[lane * 2 + j];
    float4 wv = wr[lane * 2 + j];
    dp += xv.x*wv.x + xv.y*wv.y + xv.z*wv.z + xv.w*wv.w;
    xs += xv.x*xv.x + xv.y*xv.y + xv.z*xv.z + xv.w*xv.w;
    ws += wv.x*wv.x + wv.y*wv.y + wv.z*wv.z + wv.w*wv.w;
  }
  #pragma unroll
  for (int m = 1; m < 64; m <<= 1) {
    dp += __shfl_xor(dp, m);
    xs += __shfl_xor(xs, m);
    ws += __shfl_xor(ws, m);
  }
  if (lane == 0) {
    float c = dp * rsqrtf(fmaxf(xs, 1e-24f)) * rsqrtf(fmaxf(ws, 1e-24f));
    c = fminf(fmaxf(c, -1.f), 1.f);
    float s = sqrtf(fmaxf(1.f - c * c, 0.f));
    float phi = c * C_COS_M - s * C_SIN_M;
    phi = (c > C_TH) ? phi : (c - C_MM);
    cos_t[b] = c;
    phi_t[b] = phi;
  }
}

// ---------------- 3) fused GEMM + partial sum-exp (v4) ----------------
// 512 threads = 8 waves. Wave wv owns rows [64wv, 64wv+64) x 64 classes.
// Per chunk: issue glds A(c+1) (4/wave) + glds W(c+1) fp32 (1/wave) -> ds_read
// A-frags (4 b128) + W fp32 (8 b128) -> cvt bf16 + sumsq fma -> 16 MFMA -> barrier.
// W sumsq: lane accumulates class (ct*16 + lane&15) over its k-slices; epilogue
// quad-reduce (shfl 16,32) gives per-class sumsq on every lane. No wss LDS.
__global__ __launch_bounds__(512, 4) void gemm_lse_kernel(
    const __bf16* __restrict__ xp, const float* __restrict__ w,
    float* __restrict__ gsum) {
  __shared__ __align__(16) char As[2 * NB * BK * 2];   // 2 x 32 KB bf16 (swizzled)
  __shared__ __align__(16) char Ws[2 * CT * BK * 4];   // 2 x 8 KB fp32 (swizzled)

  const int tid  = threadIdx.x;
  const int wv   = tid >> 6;          // 0..7
  const int lane = tid & 63;
  const int bc   = blockIdx.x * CT;

  // ---- per-lane W glds source (pre-swizzled gather, T21) ----
  // phys LDS offset of this lane's 16B = wv*1024 + lane*16; logical = SWZW(phys).
  const int p_w   = wv * 1024 + lane * 16;
  const int lbw   = SWZW(p_w);
  const int wrow  = min(bc + (lbw >> 7), NC - 1);
  const char* wg  = (const char*)w + (size_t)wrow * (ND * 4) + (lbw & 127);

  // ---- A glds source base ----
  const char* ag = (const char*)xp + wv * 1024 + lane * 16;

  // ---- prologue: stage chunk 0 into buffer 0 ----
  {
    char* la = As + wv * 1024;
    #pragma unroll
    for (int j = 0; j < 4; ++j)
      __builtin_amdgcn_global_load_lds((const GU*)(ag + j * 8192),
                                       (LU*)(la + j * 8192), 16, 0, 0);
    __builtin_amdgcn_global_load_lds((const GU*)wg, (LU*)(Ws + wv * 1024), 16, 0, 0);
  }

  // ---- fragment offsets (loop-invariant, swizzled) ----
  const int m_w  = wv * 64;
  const int ra   = lane & 15;
  const int quad = lane >> 4;
  int aoff[4], woff[4];
  #pragma unroll
  for (int rt = 0; rt < 4; ++rt)
    aoff[rt] = SWZA((m_w + rt * 16 + ra) * 64 + quad * 16);
  #pragma unroll
  for (int ct = 0; ct < 4; ++ct)
    woff[ct] = SWZW((ct * 16 + ra) * 128 + quad * 32);   // part1 = +16 (bit4 XOR-safe)

  f32x4 acc[4][4] = {};
  float wsq[4] = {0.f, 0.f, 0.f, 0.f};

  __syncthreads();

  for (int c = 0; c < NCHUNK; ++c) {
    const int cur = c & 1;
    if (c + 1 < NCHUNK) {
      const char* a1 = ag + (size_t)(c + 1) * (NB * BK * 2);
      char* la = As + (cur ^ 1) * (NB * BK * 2) + wv * 1024;
      #pragma unroll
      for (int j = 0; j < 4; ++j)
        __builtin_amdgcn_global_load_lds((const GU*)(a1 + j * 8192),
                                         (LU*)(la + j * 8192), 16, 0, 0);
      __builtin_amdgcn_global_load_lds((const GU*)(wg + (size_t)(c + 1) * 128),
                                       (LU*)(Ws + (cur ^ 1) * 8192 + wv * 1024),
                                       16, 0, 0);
    }

    // --- compute chunk c ---
    const char* asb = As + cur * (NB * BK * 2);
    const char* wsb = Ws + cur * 8192;
    bf16x8 af[4];
    #pragma unroll
    for (int rt = 0; rt < 4; ++rt)
      af[rt] = *reinterpret_cast<const bf16x8*>(asb + aoff[rt]);
    #pragma unroll
    for (int ct = 0; ct < 4; ++ct) {
      float4 w0 = *reinterpret_cast<const float4*>(wsb + woff[ct]);
      float4 w1 = *reinterpret_cast<const float4*>(wsb + woff[ct] + 16);
      wsq[ct] += w0.x*w0.x + w0.y*w0.y + w0.z*w0.z + w0.w*w0.w
               + w1.x*w1.x + w1.y*w1.y + w1.z*w1.z + w1.w*w1.w;
      bf16x8 bfr;
      bfr[0] = (__bf16)w0.x; bfr[1] = (__bf16)w0.y;
      bfr[2] = (__bf16)w0.z; bfr[3] = (__bf16)w0.w;
      bfr[4] = (__bf16)w1.x; bfr[5] = (__bf16)w1.y;
      bfr[6] = (__bf16)w1.z; bfr[7] = (__bf16)w1.w;
      #pragma unroll
      for (int rt = 0; rt < 4; ++rt)
        acc[rt][ct] = __builtin_amdgcn_mfma_f32_16x16x32_bf16(af[rt], bfr,
                                                              acc[rt][ct], 0, 0, 0);
    }
    __syncthreads();   // publishes buffers cur^1 (vmcnt+lgkm drained)
  }

  // ---- per-class sumsq: reduce across the 4 quads (k-slices) ----
  // lane holds partial for class ct*16 + ra over k = quad*8..+7 per chunk.
  float rnw[4];
  int   vmask[4];
  #pragma unroll
  for (int ct = 0; ct < 4; ++ct) {
    wsq[ct] += __shfl_xor(wsq[ct], 16);
    wsq[ct] += __shfl_xor(wsq[ct], 32);
    rnw[ct]   = rsqrtf(fmaxf(wsq[ct], 1e-24f));
    vmask[ct] = (bc + ct * 16 + ra) < NC;
  }

  // ---- epilogue: cosine = acc * rsqrt(|w|^2); e = exp(64*cos-64); row-sum ----
  // C/D layout (16x16): col = lane&15 (=ra, the class), row = quad*4 + reg
  float* gs = gsum + (size_t)(blockIdx.x & (REP - 1)) * NB;
  #pragma unroll
  for (int rt = 0; rt < 4; ++rt) {
    #pragma unroll
    for (int rg = 0; rg < 4; ++rg) {
      float es = 0.f;
      #pragma unroll
      for (int ct = 0; ct < 4; ++ct) {
        float cosv = acc[rt][ct][rg] * rnw[ct];
        float e = __expf(fmaf(FSCALE, cosv, -FSCALE));
        es += vmask[ct] ? e : 0.f;
      }
      es += __shfl_xor(es, 1);
      es += __shfl_xor(es, 2);
      es += __shfl_xor(es, 4);
      es += __shfl_xor(es, 8);
      if (ra == 0) {
        atomicAdd(&gs[m_w + rt * 16 + quad * 4 + rg], es);
      }
    }
  }
}

// ---------------- 4) finalize (sums REP replicas) ----------------
__global__ void finalize_kernel(const float* __restrict__ gsum,
                                const float* __restrict__ cos_t,
                                const float* __restrict__ phi_t,
                                float* __restrict__ out) {
  const int b = threadIdx.x;   // 512
  float s = 0.f;
  #pragma unroll 8
  for (int r = 0; r < REP; ++r) s += gsum[r * NB + b];
  const float c = cos_t[b];
  const float p = phi_t[b];
  float corr = s - __expf(fmaf(FSCALE, c, -FSCALE))
                 + __expf(fmaf(FSCALE, p, -FSCALE));
  corr = fmaxf(corr, 1e-38f);
  float lb = FSCALE + logf(corr) - FSCALE * p;
  #pragma unroll
  for (int m = 1; m < 64; m <<= 1) lb += __shfl_xor(lb, m);
  __shared__ float pr[8];
  if ((b & 63) == 0) pr[b >> 6] = lb;
  __syncthreads();
  if (b == 0) {
    float tot = 0.f;
    #pragma unroll
    for (int j = 0; j < 8; ++j) tot += pr[j];
    out[0] = tot * (1.0f / NB);
  }
}

extern "C" void kernel_launch(void* const* d_in, const int* in_sizes, int n_in,
                              void* d_out, int out_size, void* d_ws, size_t ws_size,
                              hipStream_t stream) {
  const float* x  = (const float*)d_in[0];
  const float* w  = (const float*)d_in[1];
  const int* tgt  = (const int*)d_in[2];
  float* out      = (float*)d_out;

  // workspace: xp (512 KB) | gsum replicas (128 KB) | cos_t (2 KB) | phi_t (2 KB)
  __bf16* xp   = (__bf16*)d_ws;
  float* gsum  = (float*)((char*)d_ws + (size_t)NB * ND * 2);
  float* cos_t = gsum + (size_t)REP * NB;
  float* phi_t = cos_t + NB;

  hipMemsetAsync(gsum, 0, (size_t)REP * NB * sizeof(float), stream);
  pack_x_kernel<<<NB, 128, 0, stream>>>(x, xp);
  cosphi_kernel<<<NB, 64, 0, stream>>>(x, w, tgt, cos_t, phi_t);
  const int nblk = (NC + CT - 1) / CT;   // 1563
  gemm_lse_kernel<<<nblk, 512, 0, stream>>>(xp, w, gsum);
  finalize_kernel<<<1, 512, 0, stream>>>(gsum, cos_t, phi_t, out);
}